// Round 7
// baseline (4615.585 us; speedup 1.0000x reference)
//
#include <hip/hip_runtime.h>

// ---------------- constants ----------------
constexpr int BATCH = 8;
constexpr int NTOK  = 4097;   // 1 cls + 4096 tokens
constexpr int NP    = 4352;   // padded seq len (multiple of 256)
constexpr int PADR  = 255;    // zero rows prepended
constexpr int EMBD  = 512;
constexpr int DHD   = 128;
constexpr int LSUB  = 17;     // NP / 256 landmarks
constexpr float SCALE_F = 0.08838834764831845f; // 128^-0.5

// PPEG padded plane: 70 rows x stride 72 (3-halo around 64x64), zeroed borders
constexpr int PPS   = 72;          // row stride
constexpr int PPLN  = 72 * 70;     // plane floats = 5040
constexpr long long TPAD_FLOATS = (long long)BATCH * EMBD * PPLN;   // 20,643,840

typedef unsigned short u16;
typedef short   s16x8 __attribute__((ext_vector_type(8)));
typedef u16     u16x4 __attribute__((ext_vector_type(4)));
typedef float   f32x4 __attribute__((ext_vector_type(4)));

__device__ __forceinline__ u16 f2bf(float x) {   // fp32 -> bf16 bits, RNE
    unsigned u = __float_as_uint(x);
    u += 0x7fffu + ((u >> 16) & 1u);
    return (u16)(u >> 16);
}
__device__ __forceinline__ float bf2f(u16 h) {
    return __uint_as_float(((unsigned)h) << 16);
}

// async global->LDS, 16B per lane; lp must be wave-uniform, gp is per-lane
__device__ __forceinline__ void gload16(const u16* gp, u16* lp) {
    __builtin_amdgcn_global_load_lds(
        (const __attribute__((address_space(1))) unsigned int*)gp,
        (__attribute__((address_space(3))) unsigned int*)lp,
        16, 0, 0);
}

// ---------------- block reductions (blockDim == 256) ----------------
__device__ __forceinline__ float block_sum256(float v) {
    __shared__ float tmp[4];
    __syncthreads();
#pragma unroll
    for (int off = 32; off > 0; off >>= 1) v += __shfl_down(v, off, 64);
    int t = threadIdx.x;
    if ((t & 63) == 0) tmp[t >> 6] = v;
    __syncthreads();
    return tmp[0] + tmp[1] + tmp[2] + tmp[3];
}

__device__ __forceinline__ float block_max256(float v) {
    __shared__ float tmp[4];
    __syncthreads();
#pragma unroll
    for (int off = 32; off > 0; off >>= 1) v = fmaxf(v, __shfl_down(v, off, 64));
    int t = threadIdx.x;
    if ((t & 63) == 0) tmp[t >> 6] = v;
    __syncthreads();
    return fmaxf(fmaxf(tmp[0], tmp[1]), fmaxf(tmp[2], tmp[3]));
}

// ---------------- generic batched GEMM via bf16x3-split MFMA (legacy path) ----
// C = cdiagc*I - [ alpha * A @ B' (+bias) ]   (transforms optional, += if accum)
struct GemmP {
    const float* A; const float* B; float* C; const float* bias;
    long long As1, As2, Bs1, Bs2, Cs1, Cs2;
    int Adiv, Bdiv, Cdiv;
    int Am, Bk, Bn, Cm, Arow, Crow;
    int M, N, K, nb;
    float alpha; int accum;
    float bdiagc; int btrans; float cdiagc; int ctrans;
};

// LDS: A-hi, A-lo, B-hi, B-lo tiles. 64 rows x 32 cols, row stride 40 u16.
constexpr int LDSTR = 40;
constexpr int AH = 0, AL = 2560, BHs = 5120, BLs = 7680;

__global__ __launch_bounds__(256) void gemm_k(GemmP p) {
    __shared__ u16 lds[10240];
    const int bz = blockIdx.z;
    const float* Ab = p.A + (long long)(bz / p.Adiv) * p.As1 + (long long)(bz % p.Adiv) * p.As2;
    const float* Bb = p.B + (long long)(bz / p.Bdiv) * p.Bs1 + (long long)(bz % p.Bdiv) * p.Bs2;
    float*       Cb = p.C + (long long)(bz / p.Cdiv) * p.Cs1 + (long long)(bz % p.Cdiv) * p.Cs2;
    const int m0 = blockIdx.y * 64, n0 = blockIdx.x * 64;
    const int t = threadIdx.x;
    const int wave = t >> 6, lane = t & 63;
    const int wm = (wave & 1) * 32, wn = (wave >> 1) * 32;
    const int quad = lane >> 4, l15 = lane & 15;

    f32x4 acc[2][2];
#pragma unroll
    for (int i = 0; i < 2; ++i)
#pragma unroll
        for (int j = 0; j < 2; ++j) acc[i][j] = (f32x4){0.f, 0.f, 0.f, 0.f};

    for (int k0 = 0; k0 < p.K; k0 += 32) {
        {
            const int ar = t >> 2, ac = (t & 3) * 8;
            float v[8];
            if (m0 + ar < p.M) {
                const float* s = Ab + (long long)(m0 + ar + p.Arow) * p.Am + (k0 + ac);
                float4 x0 = *(const float4*)s, x1 = *(const float4*)(s + 4);
                v[0] = x0.x; v[1] = x0.y; v[2] = x0.z; v[3] = x0.w;
                v[4] = x1.x; v[5] = x1.y; v[6] = x1.z; v[7] = x1.w;
            } else {
#pragma unroll
                for (int i = 0; i < 8; ++i) v[i] = 0.f;
            }
            u16 h[8], l[8];
#pragma unroll
            for (int i = 0; i < 8; ++i) { h[i] = f2bf(v[i]); l[i] = f2bf(v[i] - bf2f(h[i])); }
            const int off = ar * LDSTR + ac;
            u16x4 a0, a1, b0, b1;
#pragma unroll
            for (int i = 0; i < 4; ++i) { a0[i] = h[i]; a1[i] = h[i + 4]; b0[i] = l[i]; b1[i] = l[i + 4]; }
            *(u16x4*)&lds[AH + off] = a0; *(u16x4*)&lds[AH + off + 4] = a1;
            *(u16x4*)&lds[AL + off] = b0; *(u16x4*)&lds[AL + off + 4] = b1;
        }
        if (p.Bn == 1) {   // row-major [k][n]: coalesced read, transposed write
            const int bk = t >> 3, n8 = (t & 7) * 8;
            const float* s = Bb + (long long)(k0 + bk) * p.Bk + (n0 + n8);
            float4 x0 = *(const float4*)s, x1 = *(const float4*)(s + 4);
            float v[8] = {x0.x, x0.y, x0.z, x0.w, x1.x, x1.y, x1.z, x1.w};
            if (p.btrans) {
                const int gk = k0 + bk;
#pragma unroll
                for (int i = 0; i < 8; ++i)
                    v[i] = (gk == n0 + n8 + i ? p.bdiagc : 0.f) - v[i];
            }
#pragma unroll
            for (int i = 0; i < 8; ++i) {
                int j = (i + (t & 7)) & 7;
                u16 h = f2bf(v[j]);
                lds[BHs + (n8 + j) * LDSTR + bk] = h;
                lds[BLs + (n8 + j) * LDSTR + bk] = f2bf(v[j] - bf2f(h));
            }
        } else {           // n-major [n][k]: direct
            const int bn = t >> 2, k8 = (t & 3) * 8;
            const float* s = Bb + (long long)(n0 + bn) * p.Bn + (k0 + k8);
            float4 x0 = *(const float4*)s, x1 = *(const float4*)(s + 4);
            float v[8] = {x0.x, x0.y, x0.z, x0.w, x1.x, x1.y, x1.z, x1.w};
            u16 h[8], l[8];
#pragma unroll
            for (int i = 0; i < 8; ++i) { h[i] = f2bf(v[i]); l[i] = f2bf(v[i] - bf2f(h[i])); }
            const int off = bn * LDSTR + k8;
            u16x4 a0, a1, b0, b1;
#pragma unroll
            for (int i = 0; i < 4; ++i) { a0[i] = h[i]; a1[i] = h[i + 4]; b0[i] = l[i]; b1[i] = l[i + 4]; }
            *(u16x4*)&lds[BHs + off] = a0; *(u16x4*)&lds[BHs + off + 4] = a1;
            *(u16x4*)&lds[BLs + off] = b0; *(u16x4*)&lds[BLs + off + 4] = b1;
        }
        __syncthreads();

        s16x8 ah[2], al[2], bh[2], bl[2];
#pragma unroll
        for (int mi = 0; mi < 2; ++mi) {
            const int off = (wm + mi * 16 + l15) * LDSTR + quad * 8;
            u16x4 q0 = *(const u16x4*)&lds[AH + off], q1 = *(const u16x4*)&lds[AH + off + 4];
            u16x4 r0 = *(const u16x4*)&lds[AL + off], r1 = *(const u16x4*)&lds[AL + off + 4];
            s16x8 fh, fl;
#pragma unroll
            for (int i = 0; i < 4; ++i) { fh[i] = q0[i]; fh[i + 4] = q1[i]; fl[i] = r0[i]; fl[i + 4] = r1[i]; }
            ah[mi] = fh; al[mi] = fl;
        }
#pragma unroll
        for (int ni = 0; ni < 2; ++ni) {
            const int off = (wn + ni * 16 + l15) * LDSTR + quad * 8;
            u16x4 q0 = *(const u16x4*)&lds[BHs + off], q1 = *(const u16x4*)&lds[BHs + off + 4];
            u16x4 r0 = *(const u16x4*)&lds[BLs + off], r1 = *(const u16x4*)&lds[BLs + off + 4];
            s16x8 fh, fl;
#pragma unroll
            for (int i = 0; i < 4; ++i) { fh[i] = q0[i]; fh[i + 4] = q1[i]; fl[i] = r0[i]; fl[i + 4] = r1[i]; }
            bh[ni] = fh; bl[ni] = fl;
        }
#pragma unroll
        for (int mi = 0; mi < 2; ++mi)
#pragma unroll
            for (int ni = 0; ni < 2; ++ni) {
                acc[mi][ni] = __builtin_amdgcn_mfma_f32_16x16x32_bf16(ah[mi], bh[ni], acc[mi][ni], 0, 0, 0);
                acc[mi][ni] = __builtin_amdgcn_mfma_f32_16x16x32_bf16(ah[mi], bl[ni], acc[mi][ni], 0, 0, 0);
                acc[mi][ni] = __builtin_amdgcn_mfma_f32_16x16x32_bf16(al[mi], bh[ni], acc[mi][ni], 0, 0, 0);
            }
        __syncthreads();
    }

#pragma unroll
    for (int mi = 0; mi < 2; ++mi)
#pragma unroll
        for (int ni = 0; ni < 2; ++ni) {
            const int n = n0 + wn + ni * 16 + l15;
#pragma unroll
            for (int r = 0; r < 4; ++r) {
                const int m = m0 + wm + mi * 16 + quad * 4 + r;
                if (m >= p.M) continue;
                float v = p.alpha * acc[mi][ni][r];
                if (p.bias) v += p.bias[n];
                if (p.ctrans) v = (m == n ? p.cdiagc : 0.f) - v;
                float* dst = Cb + (long long)(m + p.Crow) * p.Cm + n;
                if (p.accum) *dst += v; else *dst = v;
            }
        }
}

// ---------------- one-time fp32 -> (hi,lo) bf16 split kernels ----------------
struct SplitP {
    const float* src; u16* dh; u16* dl;
    long long s1, s2, rstride, dstride, total;
    int div, R, C8;
    float scale;
};
__global__ __launch_bounds__(256) void split_k(SplitP p) {
    long long idx = (long long)blockIdx.x * 256 + threadIdx.x;
    if (idx >= p.total) return;
    int c8 = (int)(idx % p.C8);
    long long tmp = idx / p.C8;
    int r  = (int)(tmp % p.R);
    int bz = (int)(tmp / p.R);
    const float* s = p.src + (long long)(bz / p.div) * p.s1 + (long long)(bz % p.div) * p.s2
                   + (long long)r * p.rstride + c8 * 8;
    float4 x0 = *(const float4*)s, x1 = *(const float4*)(s + 4);
    float v[8] = {x0.x, x0.y, x0.z, x0.w, x1.x, x1.y, x1.z, x1.w};
    s16x8 hv, lv;
#pragma unroll
    for (int i = 0; i < 8; ++i) {
        float sv = v[i] * p.scale;
        u16 h = f2bf(sv);
        hv[i] = (short)h;
        lv[i] = (short)f2bf(sv - bf2f(h));
    }
    long long doff = (long long)bz * p.dstride + (long long)r * (p.C8 * 8) + c8 * 8;
    *(s16x8*)&p.dh[doff] = hv;
    *(s16x8*)&p.dl[doff] = lv;
}

// weights [K][N] row-major -> split [N][K]
__global__ __launch_bounds__(256) void splitT_k(const float* __restrict__ src,
                                                u16* __restrict__ dh, u16* __restrict__ dl,
                                                int K, int N) {
    int idx = blockIdx.x * 256 + threadIdx.x;
    if (idx >= N * K) return;
    int n = idx / K, k = idx - n * K;
    float v = src[(long long)k * N + n];
    u16 h = f2bf(v);
    dh[idx] = h;
    dl[idx] = f2bf(v - bf2f(h));
}

// batched KV [32][256][128] f32 -> KVts [32][128][256] split (B^T for ZKV)
__global__ void splitTb_k(const float* __restrict__ KV, u16* __restrict__ dh,
                          u16* __restrict__ dl) {
    long long idx = (long long)blockIdx.x * 256 + threadIdx.x;  // 32*128*256
    int k = (int)(idx & 255); int n = (int)((idx >> 8) & 127); long long bh = idx >> 15;
    float v = KV[(bh << 15) + ((long long)k << 7) + n];
    u16 h = f2bf(v);
    dh[idx] = h;
    dl[idx] = f2bf(v - bf2f(h));
}

// ---------------- pre-split bf16x3 GEMM: C = A @ B^T (+bias) ----------------
// A: [M][K] hi/lo bf16, staged via global_load_lds into linear double-buffered
// LDS (BK=32, one barrier per K-step). B: [N][K] hi/lo bf16, fragments read
// direct from L2. 128(M) x 256(N) tile, 8 waves (64x64 each).
// XCD-chunked block swizzle. [R3 champion config: 293 us QKV, MfmaUtil 23%]
struct GemmBtP {
    const u16 *Ah, *Al, *Bh, *Bl;
    float* C; const float* bias;
    long long Abs, Bbs, Cbs;
    int M, N, K, Cm, Crow, accum;
};

__global__ __launch_bounds__(512, 4) void gemm_bt_k(GemmBtP p) {
    // [buf][hi/lo][128 rows][32 u16] linear, 32 KB total
    __shared__ __align__(16) u16 lds[16384];
    const int bz = blockIdx.z;
    const u16* Ahb = p.Ah + (long long)bz * p.Abs;
    const u16* Alb = p.Al + (long long)bz * p.Abs;
    const u16* Bhb = p.Bh + (long long)bz * p.Bbs;
    const u16* Blb = p.Bl + (long long)bz * p.Bbs;
    float*     Cb  = p.C  + (long long)bz * p.Cbs;

    // bijective XCD-chunked swizzle: consecutive logical tiles share an XCD,
    // so the N-blocks sharing an A-panel hit the same L2.
    const int NX = gridDim.x;
    const int nwg = NX * gridDim.y;
    const int bid = blockIdx.y * NX + blockIdx.x;
    const int qq = nwg >> 3, rr = nwg & 7;
    const int xcd = bid & 7, loc = bid >> 3;
    const int nbid = (xcd < rr) ? (xcd * (qq + 1) + loc)
                                : (rr * (qq + 1) + (xcd - rr) * qq + loc);
    const int m0 = (nbid / NX) * 128, n0 = (nbid % NX) * 256;

    const int t = threadIdx.x;
    const int wave = t >> 6, lane = t & 63;
    const int wm = (wave & 1) * 64, wn = (wave >> 1) * 64;
    const int quad = lane >> 4, l15 = lane & 15;
    const int K = p.K;

    // staging: wave w covers rows 16w..16w+15; lane l -> row 16w+(l>>2), col 8*(l&3)
    const int srow = 16 * wave + (lane >> 2);
    const int sga  = (m0 + srow < p.M) ? (m0 + srow) : (p.M - 1);
    const long long sbase = (long long)sga * K + (lane & 3) * 8;
    u16* ldsw = &lds[wave * 512];      // wave-uniform dest base (u16 idx)

    const long long bb0   = (long long)(n0 + wn + l15) * K + quad * 8;
    const long long bstep = 16LL * K;

    f32x4 acc[4][4];
#pragma unroll
    for (int i = 0; i < 4; ++i)
#pragma unroll
        for (int j = 0; j < 4; ++j) acc[i][j] = (f32x4){0.f, 0.f, 0.f, 0.f};

    // prologue: stage tile 0 into buf 0
    gload16(Ahb + sbase, ldsw);
    gload16(Alb + sbase, ldsw + 4096);
    __syncthreads();

    const int nt = K >> 5;
    int cur = 0;
    for (int t0 = 0; t0 < nt; ++t0) {
        const int k0 = t0 << 5;
        // B fragments first (so waiting on them leaves staging in flight)
        s16x8 bh[4], bl[4];
#pragma unroll
        for (int ni = 0; ni < 4; ++ni) {
            const long long bo = bb0 + ni * bstep + k0;
            bh[ni] = *(const s16x8*)&Bhb[bo];
            bl[ni] = *(const s16x8*)&Blb[bo];
        }
        // stage next tile into the other buffer (drained by the barrier below)
        if (t0 + 1 < nt) {
            u16* dst = ldsw + (cur ^ 1) * 8192;
            gload16(Ahb + sbase + k0 + 32, dst);
            gload16(Alb + sbase + k0 + 32, dst + 4096);
        }
        // A fragments from current buffer + MFMA
        const int bufo = cur * 8192;
#pragma unroll
        for (int mi = 0; mi < 4; ++mi) {
            const int off = bufo + (wm + mi * 16 + l15) * 32 + quad * 8;
            s16x8 ah = *(const s16x8*)&lds[off];
            s16x8 al = *(const s16x8*)&lds[off + 4096];
#pragma unroll
            for (int ni = 0; ni < 4; ++ni) {
                acc[mi][ni] = __builtin_amdgcn_mfma_f32_16x16x32_bf16(ah, bh[ni], acc[mi][ni], 0, 0, 0);
                acc[mi][ni] = __builtin_amdgcn_mfma_f32_16x16x32_bf16(ah, bl[ni], acc[mi][ni], 0, 0, 0);
                acc[mi][ni] = __builtin_amdgcn_mfma_f32_16x16x32_bf16(al, bh[ni], acc[mi][ni], 0, 0, 0);
            }
        }
        __syncthreads();   // drains staging (vmcnt 0) + swaps buffers
        cur ^= 1;
    }

#pragma unroll
    for (int mi = 0; mi < 4; ++mi)
#pragma unroll
        for (int ni = 0; ni < 4; ++ni) {
            const int n = n0 + wn + ni * 16 + l15;
            const float bv = p.bias ? p.bias[n] : 0.f;
#pragma unroll
            for (int r = 0; r < 4; ++r) {
                const int m = m0 + wm + mi * 16 + quad * 4 + r;
                if (m >= p.M) continue;
                float* dst = Cb + (long long)(m + p.Crow) * p.Cm + n;
                float v = acc[mi][ni][r] + bv;
                if (p.accum) *dst += v; else *dst = v;
            }
        }
}

// ---------------- pre-split small GEMM (pinv chain): C = A @ B^T ------------
// M=256, K=256 fixed; N in {256,128}. 64x64 tile, 4 waves, NO LDS/barriers:
// all operands L2-resident, fragments read direct. Epilogue emits any of:
//   Cf (f32), CN = split(v) at [m][k=n] (normal), CT at [n][256]+m (transposed,
//   optionally ctdiag*I - v). Math/order bitwise-identical to legacy gemm_k.
struct GemmPsP {
    const u16 *Ah, *Al, *Bh, *Bl;
    float* Cf; u16 *CNh, *CNl, *CTh, *CTl;
    long long CfS;
    int N;
    float alpha; int ctrans; float cdiag; int ctsub; float ctdiag;
};

__global__ __launch_bounds__(256) void gemm_ps_k(GemmPsP p) {
    const int bz = blockIdx.z;
    const long long ab = (long long)bz << 16;                  // 256*256 u16
    const long long bb = (long long)bz * ((long long)p.N << 8);
    const u16* Ah = p.Ah + ab; const u16* Al = p.Al + ab;
    const u16* Bh = p.Bh + bb; const u16* Bl = p.Bl + bb;
    const int m0 = blockIdx.y * 64, n0 = blockIdx.x * 64;
    const int t = threadIdx.x;
    const int wave = t >> 6, lane = t & 63;
    const int wm = (wave & 1) * 32, wn = (wave >> 1) * 32;
    const int quad = lane >> 4, l15 = lane & 15;

    f32x4 acc[2][2];
#pragma unroll
    for (int i = 0; i < 2; ++i)
#pragma unroll
        for (int j = 0; j < 2; ++j) acc[i][j] = (f32x4){0.f, 0.f, 0.f, 0.f};

    const int ar = (m0 + wm + l15) * 256 + quad * 8;
    const int br = (n0 + wn + l15) * 256 + quad * 8;
    for (int k0 = 0; k0 < 256; k0 += 32) {
        s16x8 ah[2], aw[2], bh[2], bl[2];
#pragma unroll
        for (int mi = 0; mi < 2; ++mi) {
            ah[mi] = *(const s16x8*)&Ah[ar + mi * 4096 + k0];
            aw[mi] = *(const s16x8*)&Al[ar + mi * 4096 + k0];
        }
#pragma unroll
        for (int ni = 0; ni < 2; ++ni) {
            bh[ni] = *(const s16x8*)&Bh[br + ni * 4096 + k0];
            bl[ni] = *(const s16x8*)&Bl[br + ni * 4096 + k0];
        }
#pragma unroll
        for (int mi = 0; mi < 2; ++mi)
#pragma unroll
            for (int ni = 0; ni < 2; ++ni) {
                acc[mi][ni] = __builtin_amdgcn_mfma_f32_16x16x32_bf16(ah[mi], bh[ni], acc[mi][ni], 0, 0, 0);
                acc[mi][ni] = __builtin_amdgcn_mfma_f32_16x16x32_bf16(ah[mi], bl[ni], acc[mi][ni], 0, 0, 0);
                acc[mi][ni] = __builtin_amdgcn_mfma_f32_16x16x32_bf16(aw[mi], bh[ni], acc[mi][ni], 0, 0, 0);
            }
    }

#pragma unroll
    for (int mi = 0; mi < 2; ++mi)
#pragma unroll
        for (int ni = 0; ni < 2; ++ni) {
            const int n = n0 + wn + ni * 16 + l15;
#pragma unroll
            for (int r = 0; r < 4; ++r) {
                const int m = m0 + wm + mi * 16 + quad * 4 + r;
                float v = p.alpha * acc[mi][ni][r];
                if (p.ctrans) v = (m == n ? p.cdiag : 0.f) - v;
                if (p.Cf) p.Cf[(long long)bz * p.CfS + (long long)m * p.N + n] = v;
                if (p.CNh) {
                    u16 h = f2bf(v);
                    p.CNh[ab + m * 256 + n] = h;
                    p.CNl[ab + m * 256 + n] = f2bf(v - bf2f(h));
                }
                if (p.CTh) {
                    float w = p.ctsub ? ((m == n ? p.ctdiag : 0.f) - v) : v;
                    u16 h = f2bf(w);
                    p.CTh[bb + n * 256 + m] = h;
                    p.CTl[bb + n * 256 + m] = f2bf(w - bf2f(h));
                }
            }
        }
}

// ---------------- small kernels ----------------
__global__ void cls_set_k(float* H0, const float* cls) {
    int t = blockIdx.x * 256 + threadIdx.x; // 8*512
    int b = t >> 9, c = t & 511;
    H0[(long long)b * NTOK * EMBD + c] = cls[c];
}

// LN + zero-pad, emitting hi/lo bf16 split directly
__global__ __launch_bounds__(256) void ln_pad_k(const float* __restrict__ H0,
                                                u16* __restrict__ oh, u16* __restrict__ ol,
                                                const float* g, const float* bb) {
    int row = blockIdx.x, b = blockIdx.y, t = threadIdx.x;
    long long off = ((long long)b * NP + row) * EMBD;
    if (row < PADR) {
        oh[off + t] = 0; oh[off + t + 256] = 0;
        ol[off + t] = 0; ol[off + t + 256] = 0;
        return;
    }
    const float* x = H0 + ((long long)b * NTOK + (row - PADR)) * EMBD;
    float v0 = x[t], v1 = x[t + 256];
    float mu = block_sum256(v0 + v1) * (1.f / EMBD);
    float d0 = v0 - mu, d1 = v1 - mu;
    float var = block_sum256(d0 * d0 + d1 * d1) * (1.f / EMBD);
    float rs = 1.f / sqrtf(var + 1e-5f);
    float y0 = d0 * rs * g[t]       + bb[t];
    float y1 = d1 * rs * g[t + 256] + bb[t + 256];
    u16 h0 = f2bf(y0); oh[off + t]       = h0; ol[off + t]       = f2bf(y0 - bf2f(h0));
    u16 h1 = f2bf(y1); oh[off + t + 256] = h1; ol[off + t + 256] = f2bf(y1 - bf2f(h1));
}

__global__ void landmark_k(const float* __restrict__ QKV, float* __restrict__ QL,
                           float* __restrict__ KL) {
    long long idx = (long long)blockIdx.x * 256 + threadIdx.x; // 32*256*128
    int d = idx & 127; int i = (int)((idx >> 7) & 255); int bh = (int)(idx >> 15);
    int b = bh >> 2, h = bh & 3;
    const float* base = QKV + (long long)b * NP * 1536 + (long long)i * LSUB * 1536 + h * DHD + d;
    float sq = 0.f, sk = 0.f;
#pragma unroll
    for (int j = 0; j < LSUB; ++j) { sq += base[j * 1536]; sk += base[j * 1536 + EMBD]; }
    QL[idx] = sq * (1.f / LSUB);
    KL[idx] = sk * (1.f / LSUB);
}

// wave-per-row softmax for rows of exactly 256 floats
__global__ __launch_bounds__(256) void softmax256_k(float* __restrict__ X) {
    long long row = (long long)blockIdx.x * 4 + (threadIdx.x >> 6);
    int lane = threadIdx.x & 63;
    float4* p = (float4*)(X + row * 256) + lane;
    float4 v = *p;
    float m = fmaxf(fmaxf(v.x, v.y), fmaxf(v.z, v.w));
#pragma unroll
    for (int off = 32; off > 0; off >>= 1) m = fmaxf(m, __shfl_xor(m, off, 64));
    float ex = __expf(v.x - m), ey = __expf(v.y - m), ez = __expf(v.z - m), ew = __expf(v.w - m);
    float s = ex + ey + ez + ew;
#pragma unroll
    for (int off = 32; off > 0; off >>= 1) s += __shfl_xor(s, off, 64);
    float inv = 1.f / s;
    *p = make_float4(ex * inv, ey * inv, ez * inv, ew * inv);
}

// LDS-resident softmax for rows of exactly 4352 floats: 1 read + 1 write
__global__ __launch_bounds__(256) void softmax_lds_k(float* __restrict__ X) {
    __shared__ float rowbuf[4352];
    float4* p  = (float4*)(X + (long long)blockIdx.x * 4352);
    float4* r4 = (float4*)rowbuf;
    const int t = threadIdx.x;
    float m = -1e30f;
    for (int i = t; i < 1088; i += 256) {
        float4 v = p[i]; r4[i] = v;
        m = fmaxf(m, fmaxf(fmaxf(v.x, v.y), fmaxf(v.z, v.w)));
    }
    m = block_max256(m);
    float s = 0.f;
    for (int i = t; i < 1088; i += 256) {
        float4 v = r4[i];
        v.x = __expf(v.x - m); v.y = __expf(v.y - m); v.z = __expf(v.z - m); v.w = __expf(v.w - m);
        r4[i] = v;
        s += v.x + v.y + v.z + v.w;
    }
    s = block_sum256(s);
    float inv = 1.f / s;
    for (int i = t; i < 1088; i += 256) {
        float4 v = r4[i];
        p[i] = make_float4(v.x * inv, v.y * inv, v.z * inv, v.w * inv);
    }
}

__global__ __launch_bounds__(256) void pinv_absmax_k(const float* __restrict__ X, float* red) {
    int bh = blockIdx.x, t = threadIdx.x;
    const float* x = X + (long long)bh * 65536;
    float rs = 0.f, cs = 0.f;
    for (int j = 0; j < 256; ++j) { rs += fabsf(x[t * 256 + j]); cs += fabsf(x[j * 256 + t]); }
    float mr = block_max256(rs);
    float mc = block_max256(cs);
    if (t == 0) { red[bh] = mr; red[32 + bh] = mc; }
}

__global__ void pinv_scalar_k(const float* red, float* inv) {
    float mr = 0.f, mc = 0.f;
    for (int i = 0; i < 32; ++i) { mr = fmaxf(mr, red[i]); mc = fmaxf(mc, red[32 + i]); }
    inv[0] = 1.f / (mr * mc);
}

// Z0 init, both orientations, pre-split:
// Zs[c][r] = X[r][c]*inv (A-orientation of Z = X^T*inv),
// Zt[r][c] = X[r][c]*inv (B^T-orientation).  Bitwise == legacy tinit+convert.
__global__ void tinit2_k(const float* __restrict__ X, const float* __restrict__ inv,
                         u16* __restrict__ Zsh, u16* __restrict__ Zsl,
                         u16* __restrict__ Zth, u16* __restrict__ Ztl) {
    long long idx = (long long)blockIdx.x * 256 + threadIdx.x; // 32*65536
    int c = (int)(idx & 255); int r = (int)((idx >> 8) & 255); long long bh = idx >> 16;
    float v = X[idx] * inv[0];
    u16 h = f2bf(v), l = f2bf(v - bf2f(h));
    Zth[idx] = h; Ztl[idx] = l;
    long long zs = (bh << 16) + ((long long)c << 8) + r;
    Zsh[zs] = h; Zsl[zs] = l;
}

// depthwise residual conv on v (kernel 33 along seq), += into ATT2 (rows PADR..NP-1)
__global__ void resconv_k(const float* __restrict__ QKV, const float* __restrict__ rk,
                          float* __restrict__ ATT2) {
    long long idx = (long long)blockIdx.x * 256 + threadIdx.x; // 8*4097*512
    if (idx >= (long long)BATCH * NTOK * EMBD) return;
    int c = (int)(idx & 511); long long r = idx >> 9;
    int n = PADR + (int)(r % NTOK); int b = (int)(r / NTOK);
    int h = c >> 7, d = c & 127;
    const float* vb = QKV + (long long)b * NP * 1536 + 1024 + h * DHD + d;
    float acc = 0.f;
#pragma unroll
    for (int u = 0; u < 33; ++u) {
        int nn = n + u - 16;
        if (nn >= 0 && nn < NP) acc += vb[(long long)nn * 1536] * rk[h * 33 + u];
    }
    ATT2[((long long)b * NP + n) * EMBD + c] += acc;
}

// ---------------- PPEG: channel-major L1-resident stencil ----------------
__global__ void wsum_k(const float* __restrict__ k7, const float* __restrict__ k5,
                       const float* __restrict__ k3, const float* __restrict__ b7,
                       const float* __restrict__ b5, const float* __restrict__ b3,
                       float* __restrict__ W) {
    int idx = blockIdx.x * 256 + threadIdx.x;
    if (idx < 25088) {
        int c = idx / 49, i = idx - c * 49;
        int dy = i / 7, dx = i - dy * 7;
        float w = k7[idx];
        if (dy >= 1 && dy <= 5 && dx >= 1 && dx <= 5) w += k5[c * 25 + (dy - 1) * 5 + (dx - 1)];
        if (dy >= 2 && dy <= 4 && dx >= 2 && dx <= 4) w += k3[c * 9 + (dy - 2) * 3 + (dx - 2)];
        W[idx] = w;
    } else if (idx < 25600) {
        int c = idx - 25088;
        W[25088 + c] = b7[c] + b5[c] + b3[c];
    }
}

__global__ __launch_bounds__(256) void tin_k(const float* __restrict__ H0,
                                             float* __restrict__ Tpad) {
    __shared__ float lds[64][65];
    const int y = blockIdx.x, c0 = blockIdx.y * 64, b = blockIdx.z;
    const int t = threadIdx.x;
    const int pc = t & 63, pr4 = t >> 6;
    const float* src = H0 + ((long long)b * NTOK + 1 + y * 64) * EMBD + c0;
#pragma unroll
    for (int i = 0; i < 16; ++i) {
        int pr = pr4 + i * 4;
        lds[pr][pc] = src[(long long)pr * EMBD + pc];
    }
    __syncthreads();
    const int xw = t & 63, cw4 = t >> 6;
#pragma unroll
    for (int i = 0; i < 16; ++i) {
        int cw = cw4 + i * 4;
        Tpad[(long long)(b * 512 + c0 + cw) * PPLN + (3 + y) * PPS + 3 + xw] = lds[xw][cw];
    }
}

__global__ __launch_bounds__(256, 4) void conv7_k(const float* __restrict__ Tpad,
                                                  const float* __restrict__ Wall,
                                                  float* __restrict__ Tout) {
    const int bc = blockIdx.x;            // b*512 + c
    const int c = bc & 511;
    const int t = threadIdx.x;
    const int x = t & 63, band = t >> 6;  // 4 bands of 16 rows
    const int y0 = band * 16;
    const float* in = Tpad + (long long)bc * PPLN + x;
    float* outp = Tout + (long long)bc * 4096 + x;

    float W[49];
#pragma unroll
    for (int i = 0; i < 49; ++i) W[i] = Wall[c * 49 + i];
    const float bias = Wall[25088 + c];

    float win[7][7];
#pragma unroll
    for (int j = 0; j < 6; ++j)
#pragma unroll
        for (int d = 0; d < 7; ++d)
            win[j][d] = in[(y0 + j) * PPS + d];

#pragma unroll
    for (int yy = 0; yy < 16; ++yy) {
        const int slot = (6 + yy) % 7;
#pragma unroll
        for (int d = 0; d < 7; ++d)
            win[slot][d] = in[(y0 + yy + 6) * PPS + d];
        float s = bias + win[(yy + 3) % 7][3];
#pragma unroll
        for (int dy = 0; dy < 7; ++dy) {
            const int r = (yy + dy) % 7;
#pragma unroll
            for (int dx = 0; dx < 7; ++dx)
                s += W[dy * 7 + dx] * win[r][dx];
        }
        outp[(y0 + yy) * 64] = s;
    }
}

__global__ __launch_bounds__(256) void tout_k(const float* __restrict__ Tout,
                                              float* __restrict__ H0) {
    __shared__ float lds[64][65];
    const int y = blockIdx.x, c0 = blockIdx.y * 64, b = blockIdx.z;
    const int t = threadIdx.x;
    const int xl = t & 63, cl4 = t >> 6;
#pragma unroll
    for (int i = 0; i < 16; ++i) {
        int cl = cl4 + i * 4;
        lds[xl][cl] = Tout[(long long)(b * 512 + c0 + cl) * 4096 + y * 64 + xl];
    }
    __syncthreads();
    const int pc = t & 63, pl4 = t >> 6;
    float* dst = H0 + ((long long)b * NTOK + 1 + y * 64) * EMBD + c0;
#pragma unroll
    for (int i = 0; i < 16; ++i) {
        int pl = pl4 + i * 4;
        dst[(long long)pl * EMBD + pc] = lds[pl][pc];
    }
}

__global__ __launch_bounds__(256) void head_k(const float* __restrict__ H0, const float* g,
                                              const float* bb, const float* cw, const float* cb,
                                              float* __restrict__ out) {
    int b = blockIdx.x, t = threadIdx.x;
    const float* x = H0 + (long long)b * NTOK * EMBD;
    float v0 = x[t], v1 = x[t + 256];
    float mu = block_sum256(v0 + v1) * (1.f / EMBD);
    float d0 = v0 - mu, d1 = v1 - mu;
    float var = block_sum256(d0 * d0 + d1 * d1) * (1.f / EMBD);
    float rs = 1.f / sqrtf(var + 1e-5f);
    float y0 = d0 * rs * g[t] + bb[t];
    float y1 = d1 * rs * g[t + 256] + bb[t + 256];
    float s = block_sum256(y0 * cw[t] + y1 * cw[t + 256]);
    if (t == 0) out[b] = s + cb[0];
}

// ---------------- host orchestration ----------------
extern "C" void kernel_launch(void* const* d_in, const int* in_sizes, int n_in,
                              void* d_out, int out_size, void* d_ws, size_t ws_size,
                              hipStream_t stream) {
    (void)in_sizes; (void)n_in; (void)out_size; (void)ws_size;
    const float* X        = (const float*)d_in[0];
    const float* few_w    = (const float*)d_in[1];
    const float* few_b    = (const float*)d_in[2];
    const float* cls_tok  = (const float*)d_in[3];
    const float* ln_g[2]  = {(const float*)d_in[4],  (const float*)d_in[10]};
    const float* ln_b[2]  = {(const float*)d_in[5],  (const float*)d_in[11]};
    const float* qkv_w[2] = {(const float*)d_in[6],  (const float*)d_in[12]};
    const float* out_w[2] = {(const float*)d_in[7],  (const float*)d_in[13]};
    const float* out_b[2] = {(const float*)d_in[8],  (const float*)d_in[14]};
    const float* res_k[2] = {(const float*)d_in[9],  (const float*)d_in[15]};
    const float* k7 = (const float*)d_in[16]; const float* b7 = (const float*)d_in[17];
    const float* k5 = (const float*)d_in[18]; const float* b5 = (const float*)d_in[19];
    const float* k3 = (const float*)d_in[20]; const float* b3 = (const float*)d_in[21];
    const float* norm_g = (const float*)d_in[22]; const float* norm_b = (const float*)d_in[23];
    const float* cls_w  = (const float*)d_in[24]; const float* cls_b  = (const float*)d_in[25];
    float* out = (float*)d_out;

    // workspace layout (floats) — same footprint as before
    float* ws  = (float*)d_ws;
    float* H0  = ws;                         // 8*4097*512
    float* LNH = H0  + 16781312LL;           // 8*4352*512 arena (LN-split / K,Q-split / pinv split-pairs / ATT2)
    float* QKV = LNH + 17825792LL;           // 8*4352*1536  (also PPEG Tpad/Tout)
    float* A3  = QKV + 53477376LL;           // 32*256*4352  (also X-split / ATT2-split / WSUM)
    float* QL  = A3  + 35651584LL;
    float* KL  = QL  + 1048576LL;
    float* A2  = KL  + 1048576LL;            // also weight-split slot (sequential lifetime)
    float* KV  = A2  + 2097152LL;            // also QL-split (dead once KV gemm writes)
    float* ZKV = KV  + 1048576LL;            // also KL-split (dead once ZKV gemm writes)
    float* RED = ZKV + 1048576LL;

    // bf16-split overlays (all sequential lifetimes within existing regions)
    u16* LNHh = (u16*)LNH;                   // LN-out / K-split / Q-split hi
    u16* LNHl = (u16*)(LNH + 8912896LL);     // ... lo
    u16* QLh  = (u16*)KV;
    u16* QLl  = (u16*)(KV + 524288LL);
    u16* KLh  = (u16*)ZKV;
    u16* KLl  = (u16*)(ZKV + 524288LL);
    u16* Xh   = (u16*)A3;
    u16* Xl   = (u16*)(A3 + 16777216LL);
    u16* ATh  = (u16*)A3;
    u16* ATl  = (u16*)(A3 + 8390656LL);
    u16* Wh   = (u16*)A2;                    // weight hi slot (few/qkv/out, reused)
    u16* fwl  = (u16*)(A2 + 262144LL);
    u16* qwl  = (u16*)(A2 + 393216LL);
    u16* owl  = (u16*)(A2 + 131072LL);
    float* Tpad = QKV;
    float* Tout = QKV + TPAD_FLOATS;
    float* WSUM = A3;

    auto gemmx = [&](const float* A, long long As1, long long As2, int Adiv, int Am, int Arow,
                     const float* Bm, long long Bs1, long long Bs2, int Bdiv, int Bk, int Bn,
                     float* C, long long Cs1, long long Cs2, int Cdiv, int Cm, int Crow,
                     int M, int N, int K, int nb, float alpha, int accum, const float* bias,
                     float bdiagc, int btrans, float cdiagc, int ctrans) {
        GemmP p;
        p.A = A; p.B = Bm; p.C = C; p.bias = bias;
        p.As1 = As1; p.As2 = As2; p.Bs1 = Bs1; p.Bs2 = Bs2; p.Cs1 = Cs1; p.Cs2 = Cs2;
        p.Adiv = Adiv; p.Bdiv = Bdiv; p.Cdiv = Cdiv;
        p.Am = Am; p.Bk = Bk; p.Bn = Bn; p.Cm = Cm; p.Arow = Arow; p.Crow = Crow;
        p.M = M; p.N = N; p.K = K; p.nb = nb; p.alpha = alpha; p.accum = accum;
        p.bdiagc = bdiagc; p.btrans = btrans; p.cdiagc = cdiagc; p.ctrans = ctrans;
        dim3 grid(N / 64, (M + 63) / 64, nb);
        gemm_k<<<grid, 256, 0, stream>>>(p);
    };
    auto gemm = [&](const float* A, long long As1, long long As2, int Adiv, int Am, int Arow,
                    const float* Bm, long long Bs1, long long Bs2, int Bdiv, int Bk, int Bn,
                    float* C, long long Cs1, long long Cs2, int Cdiv, int Cm, int Crow,
                    int M, int N, int K, int nb, float alpha, int accum, const float* bias) {
        gemmx(A, As1, As2, Adiv, Am, Arow, Bm, Bs1, Bs2, Bdiv, Bk, Bn,
              C, Cs1, Cs2, Cdiv, Cm, Crow, M, N, K, nb, alpha, accum, bias, 0.f, 0, 0.f, 0);
    };
    auto split = [&](const float* src, u16* dh, u16* dl, long long s1, long long s2, int div,
                     long long rstride, int R, int C, int nb, float scale) {
        SplitP p;
        p.src = src; p.dh = dh; p.dl = dl;
        p.s1 = s1; p.s2 = s2; p.div = div;
        p.rstride = rstride; p.R = R; p.C8 = C >> 3;
        p.dstride = (long long)R * C;
        p.total = (long long)nb * R * (C >> 3);
        p.scale = scale;
        int blocks = (int)((p.total + 255) / 256);
        split_k<<<blocks, 256, 0, stream>>>(p);
    };
    auto gemmbt = [&](const u16* Ah, const u16* Al, long long Abs,
                      const u16* Bh, const u16* Bl, long long Bbs,
                      float* C, long long Cbs, int Cm, int Crow,
                      int M, int N, int K, int nb, int accum, const float* bias) {
        GemmBtP p;
        p.Ah = Ah; p.Al = Al; p.Bh = Bh; p.Bl = Bl;
        p.C = C; p.bias = bias;
        p.Abs = Abs; p.Bbs = Bbs; p.Cbs = Cbs;
        p.M = M; p.N = N; p.K = K; p.Cm = Cm; p.Crow = Crow; p.accum = accum;
        dim3 grid(N / 256, (M + 127) / 128, nb);
        gemm_bt_k<<<grid, 512, 0, stream>>>(p);
    };
    auto gps = [&](const u16* Ah, const u16* Al, const u16* Bh, const u16* Bl,
                   float* Cf, long long CfS, int N,
                   u16* CNh, u16* CNl, u16* CTh, u16* CTl,
                   float alpha, int ctrans, float cdiag, int ctsub, float ctdiag) {
        GemmPsP q;
        q.Ah = Ah; q.Al = Al; q.Bh = Bh; q.Bl = Bl;
        q.Cf = Cf; q.CNh = CNh; q.CNl = CNl; q.CTh = CTh; q.CTl = CTl;
        q.CfS = CfS; q.N = N;
        q.alpha = alpha; q.ctrans = ctrans; q.cdiag = cdiag;
        q.ctsub = ctsub; q.ctdiag = ctdiag;
        gemm_ps_k<<<dim3(N / 64, 4, 32), 256, 0, stream>>>(q);
    };

    // ---- stem: cls token + few-shot linear (pre-split path) ----
    cls_set_k<<<16, 256, 0, stream>>>(H0, cls_tok);
    split(X, Xh, Xl, 0, 0, 1, 1024, 32768, 1024, 1, 1.f);
    splitT_k<<<2048, 256, 0, stream>>>(few_w, Wh, fwl, 1024, 512);
    gemmbt(Xh, Xl, 4194304LL, Wh, fwl, 0,
           H0, 2097664LL, 512, 1,
           4096, 512, 1024, BATCH, 0, few_b);

    for (int L = 0; L < 2; ++L) {
        // LN (emits hi/lo bf16) + QKV projection
        ln_pad_k<<<dim3(NP, BATCH), 256, 0, stream>>>(H0, LNHh, LNHl, ln_g[L], ln_b[L]);
        splitT_k<<<3072, 256, 0, stream>>>(qkv_w[L], Wh, qwl, 512, 1536);
        gemmbt(LNHh, LNHl, 0, Wh, qwl, 0,
               QKV, 0, 1536, 0,
               34816, 1536, 512, 1, 0, nullptr);
        landmark_k<<<4096, 256, 0, stream>>>(QKV, QL, KL);
        // a2 = softmax(SCALE * QL @ KL^T)  (legacy path)
        gemm(QL, 32768LL, 0, 1, 128, 0,
             KL, 32768LL, 0, 1, 1, 128,
             A2, 65536LL, 0, 1, 256, 0,
             256, 256, 128, 32, SCALE_F, 0, nullptr);
        softmax256_k<<<2048, 256, 0, stream>>>(A2);
        // splits for a3/a1 (SCALE folded into Q-side)
        split(QL, QLh, QLl, 32768LL, 0, 1, 128, 256, 128, 32, SCALE_F);
        split(KL, KLh, KLl, 32768LL, 0, 1, 128, 256, 128, 32, 1.f);
        split(QKV + 512, LNHh, LNHl, 6680064LL, 128LL, 4, 1536, 4352, 128, 32, 1.f);  // K
        // a3 = softmax(SCALE * QL @ K^T)
        gemmbt(QLh, QLl, 32768LL, LNHh, LNHl, 557056LL,
               A3, 1114112LL, 4352, 0,
               256, 4352, 128, 32, 0, nullptr);
        softmax_lds_k<<<8192, 256, 0, stream>>>(A3);
        // KV = a3 @ V  (legacy path; V strided)
        gemm(A3, 1114112LL, 0, 1, 4352, 0,
             QKV + 1024, 6680064LL, 128LL, 4, 1536, 1,
             KV, 32768LL, 0, 1, 128, 0,
             256, 128, 4352, 32, 1.f, 0, nullptr);
        // a1 = softmax(SCALE * Q @ KL^T)  (hoisted before pinv)
        split(QKV, LNHh, LNHl, 6680064LL, 128LL, 4, 1536, 4352, 128, 32, SCALE_F);   // Q
        gemmbt(LNHh, LNHl, 557056LL, KLh, KLl, 32768LL,
               A3, 1114112LL, 256, 0,
               4352, 256, 128, 32, 0, nullptr);
        softmax256_k<<<34816, 256, 0, stream>>>(A3);

        // ---- pinv(a2): pre-split Newton chain in LNH arena (Q-split dead).
        // 8 split-pairs of [32][256][256] (2,097,152 floats each) + KVts pair.
        auto PP = [&](int i){ return (u16*)(LNH + (long long)i * 2097152LL); };
        u16 *A2sh = PP(0), *A2sl = PP(0) + 2097152;
        u16 *Zsh[2] = {PP(1), PP(3)}, *Zsl[2] = {PP(1) + 2097152, PP(3) + 2097152};
        u16 *Zth[2] = {PP(2), PP(4)}, *Ztl[2] = {PP(2) + 2097152, PP(4) + 2097152};
        u16 *XZh = PP(5), *XZl = PP(5) + 2097152;
        u16 *Tah = PP(6), *Tal = PP(6) + 2097152;   // W7ts, then U2ts
        u16 *Tbh = PP(7), *Tbl = PP(7) + 2097152;   // U1ts, then KVts host
        u16 *KVth = (u16*)(LNH + 16777216LL), *KVtl = KVth + 1048576;

        split(A2, A2sh, A2sl, 65536LL, 0, 1, 256, 256, 256, 32, 1.f);
        pinv_absmax_k<<<32, 256, 0, stream>>>(A2, RED);
        pinv_scalar_k<<<1, 1, 0, stream>>>(RED, RED + 64);
        tinit2_k<<<8192, 256, 0, stream>>>(A2, RED + 64, Zsh[0], Zsl[0], Zth[0], Ztl[0]);
        int cur = 0;
        for (int it = 0; it < 6; ++it) {
            // XZ = A2 @ Z          -> XZs (normal), W7ts = split(7I - XZ)^T
            gps(A2sh, A2sl, Zth[cur], Ztl[cur], nullptr, 0, 256,
                XZh, XZl, Tah, Tal, 1.f, 0, 0.f, 1, 7.f);
            // U1 = 15I - XZ @ W7   -> U1ts (transposed)
            gps(XZh, XZl, Tah, Tal, nullptr, 0, 256,
                nullptr, nullptr, Tbh, Tbl, 1.f, 1, 15.f, 0, 0.f);
            // U2 = 13I - XZ @ U1   -> U2ts (transposed, overwrites W7ts)
            gps(XZh, XZl, Tbh, Tbl, nullptr, 0, 256,
                nullptr, nullptr, Tah, Tal, 1.f, 1, 13.f, 0, 0.f);
            // Zn = 0.25 Z @ U2     -> Zs/Zt next
            gps(Zsh[cur], Zsl[cur], Tah, Tal, nullptr, 0, 256,
                Zsh[cur ^ 1], Zsl[cur ^ 1], Zth[cur ^ 1], Ztl[cur ^ 1],
                0.25f, 0, 0.f, 0, 0.f);
            cur ^= 1;
        }
        // ZKV = pinv @ KV  (KV transposed-split; f32 out for legacy ATT2)
        splitTb_k<<<4096, 256, 0, stream>>>(KV, KVth, KVtl);
        gps(Zsh[cur], Zsl[cur], KVth, KVtl, ZKV, 32768LL, 128,
            nullptr, nullptr, nullptr, nullptr, 1.f, 0, 0.f, 0, 0.f);

        // ATT2 = a1 @ ZKV  (legacy path; writes f32 into LNH arena)
        gemm(A3, 1114112LL, 0, 1, 256, 0,
             ZKV, 32768LL, 0, 1, 128, 1,
             LNH, 2228224LL, 128LL, 4, 512, 0,
             4352, 128, 256, 32, 1.f, 0, nullptr);
        resconv_k<<<65552, 256, 0, stream>>>(QKV, res_k[L], LNH);
        // H0 += ATT2[PADR:] @ out_w + out_b  (pre-split path)
        split(LNH + PADR * 512, ATh, ATl, 2228224LL, 0, 1, 512, 4097, 512, 8, 1.f);
        splitT_k<<<1024, 256, 0, stream>>>(out_w[L], Wh, owl, 512, 512);
        gemmbt(ATh, ATl, 2097664LL, Wh, owl, 0,
               H0, 2097664LL, 512, 0,
               4097, 512, 512, BATCH, 1, out_b[L]);

        if (L == 0) {
            hipMemsetAsync(Tpad, 0, TPAD_FLOATS * sizeof(float), stream);
            wsum_k<<<101, 256, 0, stream>>>(k7, k5, k3, b7, b5, b3, WSUM);
            tin_k<<<dim3(64, 8, 8), 256, 0, stream>>>(H0, Tpad);
            conv7_k<<<4096, 256, 0, stream>>>(Tpad, WSUM, Tout);
            tout_k<<<dim3(64, 8, 8), 256, 0, stream>>>(Tout, H0);
        }
    }

    head_k<<<BATCH, 256, 0, stream>>>(H0, norm_g, norm_b, cls_w, cls_b, out);
}

// Round 8
// 4318.451 us; speedup vs baseline: 1.0688x; 1.0688x over previous
//
#include <hip/hip_runtime.h>

// ---------------- constants ----------------
constexpr int BATCH = 8;
constexpr int NTOK  = 4097;   // 1 cls + 4096 tokens
constexpr int NP    = 4352;   // padded seq len (multiple of 256)
constexpr int PADR  = 255;    // zero rows prepended
constexpr int EMBD  = 512;
constexpr int DHD   = 128;
constexpr int LSUB  = 17;     // NP / 256 landmarks
constexpr float SCALE_F = 0.08838834764831845f; // 128^-0.5

// PPEG padded plane: 70 rows x stride 72 (3-halo around 64x64), zeroed borders
constexpr int PPS   = 72;          // row stride
constexpr int PPLN  = 72 * 70;     // plane floats = 5040
constexpr long long TPAD_FLOATS = (long long)BATCH * EMBD * PPLN;   // 20,643,840

typedef unsigned short u16;
typedef short   s16x8 __attribute__((ext_vector_type(8)));
typedef u16     u16x4 __attribute__((ext_vector_type(4)));
typedef float   f32x4 __attribute__((ext_vector_type(4)));

__device__ __forceinline__ u16 f2bf(float x) {   // fp32 -> bf16 bits, RNE
    unsigned u = __float_as_uint(x);
    u += 0x7fffu + ((u >> 16) & 1u);
    return (u16)(u >> 16);
}
__device__ __forceinline__ float bf2f(u16 h) {
    return __uint_as_float(((unsigned)h) << 16);
}

// async global->LDS, 16B per lane; lp must be wave-uniform, gp is per-lane
__device__ __forceinline__ void gload16(const u16* gp, u16* lp) {
    __builtin_amdgcn_global_load_lds(
        (const __attribute__((address_space(1))) unsigned int*)gp,
        (__attribute__((address_space(3))) unsigned int*)lp,
        16, 0, 0);
}

// ---------------- block reductions (blockDim == 256) ----------------
__device__ __forceinline__ float block_sum256(float v) {
    __shared__ float tmp[4];
    __syncthreads();
#pragma unroll
    for (int off = 32; off > 0; off >>= 1) v += __shfl_down(v, off, 64);
    int t = threadIdx.x;
    if ((t & 63) == 0) tmp[t >> 6] = v;
    __syncthreads();
    return tmp[0] + tmp[1] + tmp[2] + tmp[3];
}

__device__ __forceinline__ float block_max256(float v) {
    __shared__ float tmp[4];
    __syncthreads();
#pragma unroll
    for (int off = 32; off > 0; off >>= 1) v = fmaxf(v, __shfl_down(v, off, 64));
    int t = threadIdx.x;
    if ((t & 63) == 0) tmp[t >> 6] = v;
    __syncthreads();
    return fmaxf(fmaxf(tmp[0], tmp[1]), fmaxf(tmp[2], tmp[3]));
}

// ---------------- generic batched GEMM via bf16x3-split MFMA (legacy path) ----
// C = cdiagc*I - [ alpha * A @ B' (+bias) ]   (transforms optional, += if accum)
struct GemmP {
    const float* A; const float* B; float* C; const float* bias;
    long long As1, As2, Bs1, Bs2, Cs1, Cs2;
    int Adiv, Bdiv, Cdiv;
    int Am, Bk, Bn, Cm, Arow, Crow;
    int M, N, K, nb;
    float alpha; int accum;
    float bdiagc; int btrans; float cdiagc; int ctrans;
};

// LDS: A-hi, A-lo, B-hi, B-lo tiles. 64 rows x 32 cols, row stride 40 u16.
constexpr int LDSTR = 40;
constexpr int AH = 0, AL = 2560, BHs = 5120, BLs = 7680;

__global__ __launch_bounds__(256) void gemm_k(GemmP p) {
    __shared__ u16 lds[10240];
    const int bz = blockIdx.z;
    const float* Ab = p.A + (long long)(bz / p.Adiv) * p.As1 + (long long)(bz % p.Adiv) * p.As2;
    const float* Bb = p.B + (long long)(bz / p.Bdiv) * p.Bs1 + (long long)(bz % p.Bdiv) * p.Bs2;
    float*       Cb = p.C + (long long)(bz / p.Cdiv) * p.Cs1 + (long long)(bz % p.Cdiv) * p.Cs2;
    const int m0 = blockIdx.y * 64, n0 = blockIdx.x * 64;
    const int t = threadIdx.x;
    const int wave = t >> 6, lane = t & 63;
    const int wm = (wave & 1) * 32, wn = (wave >> 1) * 32;
    const int quad = lane >> 4, l15 = lane & 15;

    f32x4 acc[2][2];
#pragma unroll
    for (int i = 0; i < 2; ++i)
#pragma unroll
        for (int j = 0; j < 2; ++j) acc[i][j] = (f32x4){0.f, 0.f, 0.f, 0.f};

    for (int k0 = 0; k0 < p.K; k0 += 32) {
        {
            const int ar = t >> 2, ac = (t & 3) * 8;
            float v[8];
            if (m0 + ar < p.M) {
                const float* s = Ab + (long long)(m0 + ar + p.Arow) * p.Am + (k0 + ac);
                float4 x0 = *(const float4*)s, x1 = *(const float4*)(s + 4);
                v[0] = x0.x; v[1] = x0.y; v[2] = x0.z; v[3] = x0.w;
                v[4] = x1.x; v[5] = x1.y; v[6] = x1.z; v[7] = x1.w;
            } else {
#pragma unroll
                for (int i = 0; i < 8; ++i) v[i] = 0.f;
            }
            u16 h[8], l[8];
#pragma unroll
            for (int i = 0; i < 8; ++i) { h[i] = f2bf(v[i]); l[i] = f2bf(v[i] - bf2f(h[i])); }
            const int off = ar * LDSTR + ac;
            u16x4 a0, a1, b0, b1;
#pragma unroll
            for (int i = 0; i < 4; ++i) { a0[i] = h[i]; a1[i] = h[i + 4]; b0[i] = l[i]; b1[i] = l[i + 4]; }
            *(u16x4*)&lds[AH + off] = a0; *(u16x4*)&lds[AH + off + 4] = a1;
            *(u16x4*)&lds[AL + off] = b0; *(u16x4*)&lds[AL + off + 4] = b1;
        }
        if (p.Bn == 1) {   // row-major [k][n]: coalesced read, transposed write
            const int bk = t >> 3, n8 = (t & 7) * 8;
            const float* s = Bb + (long long)(k0 + bk) * p.Bk + (n0 + n8);
            float4 x0 = *(const float4*)s, x1 = *(const float4*)(s + 4);
            float v[8] = {x0.x, x0.y, x0.z, x0.w, x1.x, x1.y, x1.z, x1.w};
            if (p.btrans) {
                const int gk = k0 + bk;
#pragma unroll
                for (int i = 0; i < 8; ++i)
                    v[i] = (gk == n0 + n8 + i ? p.bdiagc : 0.f) - v[i];
            }
#pragma unroll
            for (int i = 0; i < 8; ++i) {
                int j = (i + (t & 7)) & 7;
                u16 h = f2bf(v[j]);
                lds[BHs + (n8 + j) * LDSTR + bk] = h;
                lds[BLs + (n8 + j) * LDSTR + bk] = f2bf(v[j] - bf2f(h));
            }
        } else {           // n-major [n][k]: direct
            const int bn = t >> 2, k8 = (t & 3) * 8;
            const float* s = Bb + (long long)(n0 + bn) * p.Bn + (k0 + k8);
            float4 x0 = *(const float4*)s, x1 = *(const float4*)(s + 4);
            float v[8] = {x0.x, x0.y, x0.z, x0.w, x1.x, x1.y, x1.z, x1.w};
            u16 h[8], l[8];
#pragma unroll
            for (int i = 0; i < 8; ++i) { h[i] = f2bf(v[i]); l[i] = f2bf(v[i] - bf2f(h[i])); }
            const int off = bn * LDSTR + k8;
            u16x4 a0, a1, b0, b1;
#pragma unroll
            for (int i = 0; i < 4; ++i) { a0[i] = h[i]; a1[i] = h[i + 4]; b0[i] = l[i]; b1[i] = l[i + 4]; }
            *(u16x4*)&lds[BHs + off] = a0; *(u16x4*)&lds[BHs + off + 4] = a1;
            *(u16x4*)&lds[BLs + off] = b0; *(u16x4*)&lds[BLs + off + 4] = b1;
        }
        __syncthreads();

        s16x8 ah[2], al[2], bh[2], bl[2];
#pragma unroll
        for (int mi = 0; mi < 2; ++mi) {
            const int off = (wm + mi * 16 + l15) * LDSTR + quad * 8;
            u16x4 q0 = *(const u16x4*)&lds[AH + off], q1 = *(const u16x4*)&lds[AH + off + 4];
            u16x4 r0 = *(const u16x4*)&lds[AL + off], r1 = *(const u16x4*)&lds[AL + off + 4];
            s16x8 fh, fl;
#pragma unroll
            for (int i = 0; i < 4; ++i) { fh[i] = q0[i]; fh[i + 4] = q1[i]; fl[i] = r0[i]; fl[i + 4] = r1[i]; }
            ah[mi] = fh; al[mi] = fl;
        }
#pragma unroll
        for (int ni = 0; ni < 2; ++ni) {
            const int off = (wn + ni * 16 + l15) * LDSTR + quad * 8;
            u16x4 q0 = *(const u16x4*)&lds[BHs + off], q1 = *(const u16x4*)&lds[BHs + off + 4];
            u16x4 r0 = *(const u16x4*)&lds[BLs + off], r1 = *(const u16x4*)&lds[BLs + off + 4];
            s16x8 fh, fl;
#pragma unroll
            for (int i = 0; i < 4; ++i) { fh[i] = q0[i]; fh[i + 4] = q1[i]; fl[i] = r0[i]; fl[i + 4] = r1[i]; }
            bh[ni] = fh; bl[ni] = fl;
        }
#pragma unroll
        for (int mi = 0; mi < 2; ++mi)
#pragma unroll
            for (int ni = 0; ni < 2; ++ni) {
                acc[mi][ni] = __builtin_amdgcn_mfma_f32_16x16x32_bf16(ah[mi], bh[ni], acc[mi][ni], 0, 0, 0);
                acc[mi][ni] = __builtin_amdgcn_mfma_f32_16x16x32_bf16(ah[mi], bl[ni], acc[mi][ni], 0, 0, 0);
                acc[mi][ni] = __builtin_amdgcn_mfma_f32_16x16x32_bf16(al[mi], bh[ni], acc[mi][ni], 0, 0, 0);
            }
        __syncthreads();
    }

#pragma unroll
    for (int mi = 0; mi < 2; ++mi)
#pragma unroll
        for (int ni = 0; ni < 2; ++ni) {
            const int n = n0 + wn + ni * 16 + l15;
#pragma unroll
            for (int r = 0; r < 4; ++r) {
                const int m = m0 + wm + mi * 16 + quad * 4 + r;
                if (m >= p.M) continue;
                float v = p.alpha * acc[mi][ni][r];
                if (p.bias) v += p.bias[n];
                if (p.ctrans) v = (m == n ? p.cdiagc : 0.f) - v;
                float* dst = Cb + (long long)(m + p.Crow) * p.Cm + n;
                if (p.accum) *dst += v; else *dst = v;
            }
        }
}

// ---------------- one-time fp32 -> (hi,lo) bf16 split kernels ----------------
struct SplitP {
    const float* src; u16* dh; u16* dl;
    long long s1, s2, rstride, dstride, total;
    int div, R, C8;
    float scale;
};
__global__ __launch_bounds__(256) void split_k(SplitP p) {
    long long idx = (long long)blockIdx.x * 256 + threadIdx.x;
    if (idx >= p.total) return;
    int c8 = (int)(idx % p.C8);
    long long tmp = idx / p.C8;
    int r  = (int)(tmp % p.R);
    int bz = (int)(tmp / p.R);
    const float* s = p.src + (long long)(bz / p.div) * p.s1 + (long long)(bz % p.div) * p.s2
                   + (long long)r * p.rstride + c8 * 8;
    float4 x0 = *(const float4*)s, x1 = *(const float4*)(s + 4);
    float v[8] = {x0.x, x0.y, x0.z, x0.w, x1.x, x1.y, x1.z, x1.w};
    s16x8 hv, lv;
#pragma unroll
    for (int i = 0; i < 8; ++i) {
        float sv = v[i] * p.scale;
        u16 h = f2bf(sv);
        hv[i] = (short)h;
        lv[i] = (short)f2bf(sv - bf2f(h));
    }
    long long doff = (long long)bz * p.dstride + (long long)r * (p.C8 * 8) + c8 * 8;
    *(s16x8*)&p.dh[doff] = hv;
    *(s16x8*)&p.dl[doff] = lv;
}

// weights [K][N] row-major -> split [N][K]
__global__ __launch_bounds__(256) void splitT_k(const float* __restrict__ src,
                                                u16* __restrict__ dh, u16* __restrict__ dl,
                                                int K, int N) {
    int idx = blockIdx.x * 256 + threadIdx.x;
    if (idx >= N * K) return;
    int n = idx / K, k = idx - n * K;
    float v = src[(long long)k * N + n];
    u16 h = f2bf(v);
    dh[idx] = h;
    dl[idx] = f2bf(v - bf2f(h));
}

// ---------------- pre-split bf16x3 GEMM: C = A @ B^T (+bias) ----------------
// A: [M][K] hi/lo bf16, staged via global_load_lds into linear double-buffered
// LDS (BK=32, one barrier per K-step). B: [N][K] hi/lo bf16, fragments read
// direct from L2. 128(M) x 256(N) tile, 8 waves (64x64 each).
// XCD-chunked block swizzle. [R3 champion config: 293 us QKV, MfmaUtil 23%]
struct GemmBtP {
    const u16 *Ah, *Al, *Bh, *Bl;
    float* C; const float* bias;
    long long Abs, Bbs, Cbs;
    int M, N, K, Cm, Crow, accum;
};

__global__ __launch_bounds__(512, 4) void gemm_bt_k(GemmBtP p) {
    // [buf][hi/lo][128 rows][32 u16] linear, 32 KB total
    __shared__ __align__(16) u16 lds[16384];
    const int bz = blockIdx.z;
    const u16* Ahb = p.Ah + (long long)bz * p.Abs;
    const u16* Alb = p.Al + (long long)bz * p.Abs;
    const u16* Bhb = p.Bh + (long long)bz * p.Bbs;
    const u16* Blb = p.Bl + (long long)bz * p.Bbs;
    float*     Cb  = p.C  + (long long)bz * p.Cbs;

    // bijective XCD-chunked swizzle: consecutive logical tiles share an XCD,
    // so the N-blocks sharing an A-panel hit the same L2.
    const int NX = gridDim.x;
    const int nwg = NX * gridDim.y;
    const int bid = blockIdx.y * NX + blockIdx.x;
    const int qq = nwg >> 3, rr = nwg & 7;
    const int xcd = bid & 7, loc = bid >> 3;
    const int nbid = (xcd < rr) ? (xcd * (qq + 1) + loc)
                                : (rr * (qq + 1) + (xcd - rr) * qq + loc);
    const int m0 = (nbid / NX) * 128, n0 = (nbid % NX) * 256;

    const int t = threadIdx.x;
    const int wave = t >> 6, lane = t & 63;
    const int wm = (wave & 1) * 64, wn = (wave >> 1) * 64;
    const int quad = lane >> 4, l15 = lane & 15;
    const int K = p.K;

    // staging: wave w covers rows 16w..16w+15; lane l -> row 16w+(l>>2), col 8*(l&3)
    const int srow = 16 * wave + (lane >> 2);
    const int sga  = (m0 + srow < p.M) ? (m0 + srow) : (p.M - 1);
    const long long sbase = (long long)sga * K + (lane & 3) * 8;
    u16* ldsw = &lds[wave * 512];      // wave-uniform dest base (u16 idx)

    const long long bb0   = (long long)(n0 + wn + l15) * K + quad * 8;
    const long long bstep = 16LL * K;

    f32x4 acc[4][4];
#pragma unroll
    for (int i = 0; i < 4; ++i)
#pragma unroll
        for (int j = 0; j < 4; ++j) acc[i][j] = (f32x4){0.f, 0.f, 0.f, 0.f};

    // prologue: stage tile 0 into buf 0
    gload16(Ahb + sbase, ldsw);
    gload16(Alb + sbase, ldsw + 4096);
    __syncthreads();

    const int nt = K >> 5;
    int cur = 0;
    for (int t0 = 0; t0 < nt; ++t0) {
        const int k0 = t0 << 5;
        // B fragments first (so waiting on them leaves staging in flight)
        s16x8 bh[4], bl[4];
#pragma unroll
        for (int ni = 0; ni < 4; ++ni) {
            const long long bo = bb0 + ni * bstep + k0;
            bh[ni] = *(const s16x8*)&Bhb[bo];
            bl[ni] = *(const s16x8*)&Blb[bo];
        }
        // stage next tile into the other buffer (drained by the barrier below)
        if (t0 + 1 < nt) {
            u16* dst = ldsw + (cur ^ 1) * 8192;
            gload16(Ahb + sbase + k0 + 32, dst);
            gload16(Alb + sbase + k0 + 32, dst + 4096);
        }
        // A fragments from current buffer + MFMA
        const int bufo = cur * 8192;
#pragma unroll
        for (int mi = 0; mi < 4; ++mi) {
            const int off = bufo + (wm + mi * 16 + l15) * 32 + quad * 8;
            s16x8 ah = *(const s16x8*)&lds[off];
            s16x8 al = *(const s16x8*)&lds[off + 4096];
#pragma unroll
            for (int ni = 0; ni < 4; ++ni) {
                acc[mi][ni] = __builtin_amdgcn_mfma_f32_16x16x32_bf16(ah, bh[ni], acc[mi][ni], 0, 0, 0);
                acc[mi][ni] = __builtin_amdgcn_mfma_f32_16x16x32_bf16(ah, bl[ni], acc[mi][ni], 0, 0, 0);
                acc[mi][ni] = __builtin_amdgcn_mfma_f32_16x16x32_bf16(al, bh[ni], acc[mi][ni], 0, 0, 0);
            }
        }
        __syncthreads();   // drains staging (vmcnt 0) + swaps buffers
        cur ^= 1;
    }

#pragma unroll
    for (int mi = 0; mi < 4; ++mi)
#pragma unroll
        for (int ni = 0; ni < 4; ++ni) {
            const int n = n0 + wn + ni * 16 + l15;
            const float bv = p.bias ? p.bias[n] : 0.f;
#pragma unroll
            for (int r = 0; r < 4; ++r) {
                const int m = m0 + wm + mi * 16 + quad * 4 + r;
                if (m >= p.M) continue;
                float* dst = Cb + (long long)(m + p.Crow) * p.Cm + n;
                float v = acc[mi][ni][r] + bv;
                if (p.accum) *dst += v; else *dst = v;
            }
        }
}

// ---------------- small kernels ----------------
__global__ void cls_set_k(float* H0, const float* cls) {
    int t = blockIdx.x * 256 + threadIdx.x; // 8*512
    int b = t >> 9, c = t & 511;
    H0[(long long)b * NTOK * EMBD + c] = cls[c];
}

// LN + zero-pad, emitting hi/lo bf16 split directly
__global__ __launch_bounds__(256) void ln_pad_k(const float* __restrict__ H0,
                                                u16* __restrict__ oh, u16* __restrict__ ol,
                                                const float* g, const float* bb) {
    int row = blockIdx.x, b = blockIdx.y, t = threadIdx.x;
    long long off = ((long long)b * NP + row) * EMBD;
    if (row < PADR) {
        oh[off + t] = 0; oh[off + t + 256] = 0;
        ol[off + t] = 0; ol[off + t + 256] = 0;
        return;
    }
    const float* x = H0 + ((long long)b * NTOK + (row - PADR)) * EMBD;
    float v0 = x[t], v1 = x[t + 256];
    float mu = block_sum256(v0 + v1) * (1.f / EMBD);
    float d0 = v0 - mu, d1 = v1 - mu;
    float var = block_sum256(d0 * d0 + d1 * d1) * (1.f / EMBD);
    float rs = 1.f / sqrtf(var + 1e-5f);
    float y0 = d0 * rs * g[t]       + bb[t];
    float y1 = d1 * rs * g[t + 256] + bb[t + 256];
    u16 h0 = f2bf(y0); oh[off + t]       = h0; ol[off + t]       = f2bf(y0 - bf2f(h0));
    u16 h1 = f2bf(y1); oh[off + t + 256] = h1; ol[off + t + 256] = f2bf(y1 - bf2f(h1));
}

__global__ void landmark_k(const float* __restrict__ QKV, float* __restrict__ QL,
                           float* __restrict__ KL) {
    long long idx = (long long)blockIdx.x * 256 + threadIdx.x; // 32*256*128
    int d = idx & 127; int i = (int)((idx >> 7) & 255); int bh = (int)(idx >> 15);
    int b = bh >> 2, h = bh & 3;
    const float* base = QKV + (long long)b * NP * 1536 + (long long)i * LSUB * 1536 + h * DHD + d;
    float sq = 0.f, sk = 0.f;
#pragma unroll
    for (int j = 0; j < LSUB; ++j) { sq += base[j * 1536]; sk += base[j * 1536 + EMBD]; }
    QL[idx] = sq * (1.f / LSUB);
    KL[idx] = sk * (1.f / LSUB);
}

// wave-per-row softmax for rows of exactly 256 floats
__global__ __launch_bounds__(256) void softmax256_k(float* __restrict__ X) {
    long long row = (long long)blockIdx.x * 4 + (threadIdx.x >> 6);
    int lane = threadIdx.x & 63;
    float4* p = (float4*)(X + row * 256) + lane;
    float4 v = *p;
    float m = fmaxf(fmaxf(v.x, v.y), fmaxf(v.z, v.w));
#pragma unroll
    for (int off = 32; off > 0; off >>= 1) m = fmaxf(m, __shfl_xor(m, off, 64));
    float ex = __expf(v.x - m), ey = __expf(v.y - m), ez = __expf(v.z - m), ew = __expf(v.w - m);
    float s = ex + ey + ez + ew;
#pragma unroll
    for (int off = 32; off > 0; off >>= 1) s += __shfl_xor(s, off, 64);
    float inv = 1.f / s;
    *p = make_float4(ex * inv, ey * inv, ez * inv, ew * inv);
}

// LDS-resident softmax for rows of exactly 4352 floats: 1 read + 1 write
__global__ __launch_bounds__(256) void softmax_lds_k(float* __restrict__ X) {
    __shared__ float rowbuf[4352];
    float4* p  = (float4*)(X + (long long)blockIdx.x * 4352);
    float4* r4 = (float4*)rowbuf;
    const int t = threadIdx.x;
    float m = -1e30f;
    for (int i = t; i < 1088; i += 256) {
        float4 v = p[i]; r4[i] = v;
        m = fmaxf(m, fmaxf(fmaxf(v.x, v.y), fmaxf(v.z, v.w)));
    }
    m = block_max256(m);
    float s = 0.f;
    for (int i = t; i < 1088; i += 256) {
        float4 v = r4[i];
        v.x = __expf(v.x - m); v.y = __expf(v.y - m); v.z = __expf(v.z - m); v.w = __expf(v.w - m);
        r4[i] = v;
        s += v.x + v.y + v.z + v.w;
    }
    s = block_sum256(s);
    float inv = 1.f / s;
    for (int i = t; i < 1088; i += 256) {
        float4 v = r4[i];
        p[i] = make_float4(v.x * inv, v.y * inv, v.z * inv, v.w * inv);
    }
}

__global__ __launch_bounds__(256) void pinv_absmax_k(const float* __restrict__ X, float* red) {
    int bh = blockIdx.x, t = threadIdx.x;
    const float* x = X + (long long)bh * 65536;
    float rs = 0.f, cs = 0.f;
    for (int j = 0; j < 256; ++j) { rs += fabsf(x[t * 256 + j]); cs += fabsf(x[j * 256 + t]); }
    float mr = block_max256(rs);
    float mc = block_max256(cs);
    if (t == 0) { red[bh] = mr; red[32 + bh] = mc; }
}

__global__ void pinv_scalar_k(const float* red, float* inv) {
    float mr = 0.f, mc = 0.f;
    for (int i = 0; i < 32; ++i) { mr = fmaxf(mr, red[i]); mc = fmaxf(mc, red[32 + i]); }
    inv[0] = 1.f / (mr * mc);
}

__global__ void pinv_tinit_k(const float* __restrict__ X, const float* __restrict__ inv,
                             float* __restrict__ Z) {
    long long idx = (long long)blockIdx.x * 256 + threadIdx.x; // 32*65536
    int j = (int)(idx & 255); int i = (int)((idx >> 8) & 255); long long bh = idx >> 16;
    Z[idx] = X[(bh << 16) + ((long long)j << 8) + i] * inv[0];
}

// depthwise residual conv on v (kernel 33 along seq), += into ATT2 (rows PADR..NP-1)
__global__ void resconv_k(const float* __restrict__ QKV, const float* __restrict__ rk,
                          float* __restrict__ ATT2) {
    long long idx = (long long)blockIdx.x * 256 + threadIdx.x; // 8*4097*512
    if (idx >= (long long)BATCH * NTOK * EMBD) return;
    int c = (int)(idx & 511); long long r = idx >> 9;
    int n = PADR + (int)(r % NTOK); int b = (int)(r / NTOK);
    int h = c >> 7, d = c & 127;
    const float* vb = QKV + (long long)b * NP * 1536 + 1024 + h * DHD + d;
    float acc = 0.f;
#pragma unroll
    for (int u = 0; u < 33; ++u) {
        int nn = n + u - 16;
        if (nn >= 0 && nn < NP) acc += vb[(long long)nn * 1536] * rk[h * 33 + u];
    }
    ATT2[((long long)b * NP + n) * EMBD + c] += acc;
}

// ---------------- PPEG: channel-major L1-resident stencil ----------------
__global__ void wsum_k(const float* __restrict__ k7, const float* __restrict__ k5,
                       const float* __restrict__ k3, const float* __restrict__ b7,
                       const float* __restrict__ b5, const float* __restrict__ b3,
                       float* __restrict__ W) {
    int idx = blockIdx.x * 256 + threadIdx.x;
    if (idx < 25088) {
        int c = idx / 49, i = idx - c * 49;
        int dy = i / 7, dx = i - dy * 7;
        float w = k7[idx];
        if (dy >= 1 && dy <= 5 && dx >= 1 && dx <= 5) w += k5[c * 25 + (dy - 1) * 5 + (dx - 1)];
        if (dy >= 2 && dy <= 4 && dx >= 2 && dx <= 4) w += k3[c * 9 + (dy - 2) * 3 + (dx - 2)];
        W[idx] = w;
    } else if (idx < 25600) {
        int c = idx - 25088;
        W[25088 + c] = b7[c] + b5[c] + b3[c];
    }
}

__global__ __launch_bounds__(256) void tin_k(const float* __restrict__ H0,
                                             float* __restrict__ Tpad) {
    __shared__ float lds[64][65];
    const int y = blockIdx.x, c0 = blockIdx.y * 64, b = blockIdx.z;
    const int t = threadIdx.x;
    const int pc = t & 63, pr4 = t >> 6;
    const float* src = H0 + ((long long)b * NTOK + 1 + y * 64) * EMBD + c0;
#pragma unroll
    for (int i = 0; i < 16; ++i) {
        int pr = pr4 + i * 4;
        lds[pr][pc] = src[(long long)pr * EMBD + pc];
    }
    __syncthreads();
    const int xw = t & 63, cw4 = t >> 6;
#pragma unroll
    for (int i = 0; i < 16; ++i) {
        int cw = cw4 + i * 4;
        Tpad[(long long)(b * 512 + c0 + cw) * PPLN + (3 + y) * PPS + 3 + xw] = lds[xw][cw];
    }
}

__global__ __launch_bounds__(256, 4) void conv7_k(const float* __restrict__ Tpad,
                                                  const float* __restrict__ Wall,
                                                  float* __restrict__ Tout) {
    const int bc = blockIdx.x;            // b*512 + c
    const int c = bc & 511;
    const int t = threadIdx.x;
    const int x = t & 63, band = t >> 6;  // 4 bands of 16 rows
    const int y0 = band * 16;
    const float* in = Tpad + (long long)bc * PPLN + x;
    float* outp = Tout + (long long)bc * 4096 + x;

    float W[49];
#pragma unroll
    for (int i = 0; i < 49; ++i) W[i] = Wall[c * 49 + i];
    const float bias = Wall[25088 + c];

    float win[7][7];
#pragma unroll
    for (int j = 0; j < 6; ++j)
#pragma unroll
        for (int d = 0; d < 7; ++d)
            win[j][d] = in[(y0 + j) * PPS + d];

#pragma unroll
    for (int yy = 0; yy < 16; ++yy) {
        const int slot = (6 + yy) % 7;
#pragma unroll
        for (int d = 0; d < 7; ++d)
            win[slot][d] = in[(y0 + yy + 6) * PPS + d];
        float s = bias + win[(yy + 3) % 7][3];
#pragma unroll
        for (int dy = 0; dy < 7; ++dy) {
            const int r = (yy + dy) % 7;
#pragma unroll
            for (int dx = 0; dx < 7; ++dx)
                s += W[dy * 7 + dx] * win[r][dx];
        }
        outp[(y0 + yy) * 64] = s;
    }
}

__global__ __launch_bounds__(256) void tout_k(const float* __restrict__ Tout,
                                              float* __restrict__ H0) {
    __shared__ float lds[64][65];
    const int y = blockIdx.x, c0 = blockIdx.y * 64, b = blockIdx.z;
    const int t = threadIdx.x;
    const int xl = t & 63, cl4 = t >> 6;
#pragma unroll
    for (int i = 0; i < 16; ++i) {
        int cl = cl4 + i * 4;
        lds[xl][cl] = Tout[(long long)(b * 512 + c0 + cl) * 4096 + y * 64 + xl];
    }
    __syncthreads();
    const int pc = t & 63, pl4 = t >> 6;
    float* dst = H0 + ((long long)b * NTOK + 1 + y * 64) * EMBD + c0;
#pragma unroll
    for (int i = 0; i < 16; ++i) {
        int pl = pl4 + i * 4;
        dst[(long long)pl * EMBD + pc] = lds[pl][pc];
    }
}

__global__ __launch_bounds__(256) void head_k(const float* __restrict__ H0, const float* g,
                                              const float* bb, const float* cw, const float* cb,
                                              float* __restrict__ out) {
    int b = blockIdx.x, t = threadIdx.x;
    const float* x = H0 + (long long)b * NTOK * EMBD;
    float v0 = x[t], v1 = x[t + 256];
    float mu = block_sum256(v0 + v1) * (1.f / EMBD);
    float d0 = v0 - mu, d1 = v1 - mu;
    float var = block_sum256(d0 * d0 + d1 * d1) * (1.f / EMBD);
    float rs = 1.f / sqrtf(var + 1e-5f);
    float y0 = d0 * rs * g[t] + bb[t];
    float y1 = d1 * rs * g[t + 256] + bb[t + 256];
    float s = block_sum256(y0 * cw[t] + y1 * cw[t + 256]);
    if (t == 0) out[b] = s + cb[0];
}

// ---------------- host orchestration ----------------
extern "C" void kernel_launch(void* const* d_in, const int* in_sizes, int n_in,
                              void* d_out, int out_size, void* d_ws, size_t ws_size,
                              hipStream_t stream) {
    (void)in_sizes; (void)n_in; (void)out_size; (void)ws_size;
    const float* X        = (const float*)d_in[0];
    const float* few_w    = (const float*)d_in[1];
    const float* few_b    = (const float*)d_in[2];
    const float* cls_tok  = (const float*)d_in[3];
    const float* ln_g[2]  = {(const float*)d_in[4],  (const float*)d_in[10]};
    const float* ln_b[2]  = {(const float*)d_in[5],  (const float*)d_in[11]};
    const float* qkv_w[2] = {(const float*)d_in[6],  (const float*)d_in[12]};
    const float* out_w[2] = {(const float*)d_in[7],  (const float*)d_in[13]};
    const float* out_b[2] = {(const float*)d_in[8],  (const float*)d_in[14]};
    const float* res_k[2] = {(const float*)d_in[9],  (const float*)d_in[15]};
    const float* k7 = (const float*)d_in[16]; const float* b7 = (const float*)d_in[17];
    const float* k5 = (const float*)d_in[18]; const float* b5 = (const float*)d_in[19];
    const float* k3 = (const float*)d_in[20]; const float* b3 = (const float*)d_in[21];
    const float* norm_g = (const float*)d_in[22]; const float* norm_b = (const float*)d_in[23];
    const float* cls_w  = (const float*)d_in[24]; const float* cls_b  = (const float*)d_in[25];
    float* out = (float*)d_out;

    // workspace layout (floats) — same footprint as before
    float* ws  = (float*)d_ws;
    float* H0  = ws;                         // 8*4097*512
    float* LNH = H0  + 16781312LL;           // 8*4352*512 arena (LN-split / K,Q-split / pinv temps / ATT2)
    float* QKV = LNH + 17825792LL;           // 8*4352*1536  (also PPEG Tpad/Tout)
    float* A3  = QKV + 53477376LL;           // 32*256*4352  (also X-split / ATT2-split / WSUM)
    float* QL  = A3  + 35651584LL;
    float* KL  = QL  + 1048576LL;
    float* A2  = KL  + 1048576LL;            // also weight-split slot (sequential lifetime)
    float* KV  = A2  + 2097152LL;            // also QL-split (dead once KV gemm writes)
    float* ZKV = KV  + 1048576LL;            // also KL-split (dead once ZKV gemm writes)
    float* RED = ZKV + 1048576LL;

    // bf16-split overlays (all sequential lifetimes within existing regions)
    u16* LNHh = (u16*)LNH;                   // LN-out / K-split / Q-split hi
    u16* LNHl = (u16*)(LNH + 8912896LL);     // ... lo
    u16* QLh  = (u16*)KV;
    u16* QLl  = (u16*)(KV + 524288LL);
    u16* KLh  = (u16*)ZKV;
    u16* KLl  = (u16*)(ZKV + 524288LL);
    u16* Xh   = (u16*)A3;
    u16* Xl   = (u16*)(A3 + 16777216LL);
    u16* ATh  = (u16*)A3;
    u16* ATl  = (u16*)(A3 + 8390656LL);
    u16* Wh   = (u16*)A2;                    // weight hi slot (few/qkv/out, reused)
    u16* fwl  = (u16*)(A2 + 262144LL);
    u16* qwl  = (u16*)(A2 + 393216LL);
    u16* owl  = (u16*)(A2 + 131072LL);
    // pinv temps live in the LNH arena (free between a1 gemm and ATT2 gemm)
    float* Zb0 = LNH;
    float* Zb1 = LNH + 2097152LL;
    float* XZm = LNH + 4194304LL;
    float* U1  = LNH + 6291456LL;
    float* U2  = LNH + 8388608LL;
    float* Tpad = QKV;
    float* Tout = QKV + TPAD_FLOATS;
    float* WSUM = A3;

    auto gemmx = [&](const float* A, long long As1, long long As2, int Adiv, int Am, int Arow,
                     const float* Bm, long long Bs1, long long Bs2, int Bdiv, int Bk, int Bn,
                     float* C, long long Cs1, long long Cs2, int Cdiv, int Cm, int Crow,
                     int M, int N, int K, int nb, float alpha, int accum, const float* bias,
                     float bdiagc, int btrans, float cdiagc, int ctrans) {
        GemmP p;
        p.A = A; p.B = Bm; p.C = C; p.bias = bias;
        p.As1 = As1; p.As2 = As2; p.Bs1 = Bs1; p.Bs2 = Bs2; p.Cs1 = Cs1; p.Cs2 = Cs2;
        p.Adiv = Adiv; p.Bdiv = Bdiv; p.Cdiv = Cdiv;
        p.Am = Am; p.Bk = Bk; p.Bn = Bn; p.Cm = Cm; p.Arow = Arow; p.Crow = Crow;
        p.M = M; p.N = N; p.K = K; p.nb = nb; p.alpha = alpha; p.accum = accum;
        p.bdiagc = bdiagc; p.btrans = btrans; p.cdiagc = cdiagc; p.ctrans = ctrans;
        dim3 grid(N / 64, (M + 63) / 64, nb);
        gemm_k<<<grid, 256, 0, stream>>>(p);
    };
    auto gemm = [&](const float* A, long long As1, long long As2, int Adiv, int Am, int Arow,
                    const float* Bm, long long Bs1, long long Bs2, int Bdiv, int Bk, int Bn,
                    float* C, long long Cs1, long long Cs2, int Cdiv, int Cm, int Crow,
                    int M, int N, int K, int nb, float alpha, int accum, const float* bias) {
        gemmx(A, As1, As2, Adiv, Am, Arow, Bm, Bs1, Bs2, Bdiv, Bk, Bn,
              C, Cs1, Cs2, Cdiv, Cm, Crow, M, N, K, nb, alpha, accum, bias, 0.f, 0, 0.f, 0);
    };
    auto split = [&](const float* src, u16* dh, u16* dl, long long s1, long long s2, int div,
                     long long rstride, int R, int C, int nb, float scale) {
        SplitP p;
        p.src = src; p.dh = dh; p.dl = dl;
        p.s1 = s1; p.s2 = s2; p.div = div;
        p.rstride = rstride; p.R = R; p.C8 = C >> 3;
        p.dstride = (long long)R * C;
        p.total = (long long)nb * R * (C >> 3);
        p.scale = scale;
        int blocks = (int)((p.total + 255) / 256);
        split_k<<<blocks, 256, 0, stream>>>(p);
    };
    auto gemmbt = [&](const u16* Ah, const u16* Al, long long Abs,
                      const u16* Bh, const u16* Bl, long long Bbs,
                      float* C, long long Cbs, int Cm, int Crow,
                      int M, int N, int K, int nb, int accum, const float* bias) {
        GemmBtP p;
        p.Ah = Ah; p.Al = Al; p.Bh = Bh; p.Bl = Bl;
        p.C = C; p.bias = bias;
        p.Abs = Abs; p.Bbs = Bbs; p.Cbs = Cbs;
        p.M = M; p.N = N; p.K = K; p.Cm = Cm; p.Crow = Crow; p.accum = accum;
        dim3 grid(N / 256, (M + 127) / 128, nb);
        gemm_bt_k<<<grid, 512, 0, stream>>>(p);
    };

    // ---- stem: cls token + few-shot linear (pre-split path) ----
    cls_set_k<<<16, 256, 0, stream>>>(H0, cls_tok);
    split(X, Xh, Xl, 0, 0, 1, 1024, 32768, 1024, 1, 1.f);
    splitT_k<<<2048, 256, 0, stream>>>(few_w, Wh, fwl, 1024, 512);
    gemmbt(Xh, Xl, 4194304LL, Wh, fwl, 0,
           H0, 2097664LL, 512, 1,
           4096, 512, 1024, BATCH, 0, few_b);

    for (int L = 0; L < 2; ++L) {
        // LN (emits hi/lo bf16) + QKV projection
        ln_pad_k<<<dim3(NP, BATCH), 256, 0, stream>>>(H0, LNHh, LNHl, ln_g[L], ln_b[L]);
        splitT_k<<<3072, 256, 0, stream>>>(qkv_w[L], Wh, qwl, 512, 1536);
        gemmbt(LNHh, LNHl, 0, Wh, qwl, 0,
               QKV, 0, 1536, 0,
               34816, 1536, 512, 1, 0, nullptr);
        landmark_k<<<4096, 256, 0, stream>>>(QKV, QL, KL);
        // a2 = softmax(SCALE * QL @ KL^T)  (legacy path)
        gemm(QL, 32768LL, 0, 1, 128, 0,
             KL, 32768LL, 0, 1, 1, 128,
             A2, 65536LL, 0, 1, 256, 0,
             256, 256, 128, 32, SCALE_F, 0, nullptr);
        softmax256_k<<<2048, 256, 0, stream>>>(A2);
        // splits for a3/a1 (SCALE folded into Q-side)
        split(QL, QLh, QLl, 32768LL, 0, 1, 128, 256, 128, 32, SCALE_F);
        split(KL, KLh, KLl, 32768LL, 0, 1, 128, 256, 128, 32, 1.f);
        split(QKV + 512, LNHh, LNHl, 6680064LL, 128LL, 4, 1536, 4352, 128, 32, 1.f);  // K
        // a3 = softmax(SCALE * QL @ K^T)
        gemmbt(QLh, QLl, 32768LL, LNHh, LNHl, 557056LL,
               A3, 1114112LL, 4352, 0,
               256, 4352, 128, 32, 0, nullptr);
        softmax_lds_k<<<8192, 256, 0, stream>>>(A3);
        // KV = a3 @ V  (legacy path; V strided)
        gemm(A3, 1114112LL, 0, 1, 4352, 0,
             QKV + 1024, 6680064LL, 128LL, 4, 1536, 1,
             KV, 32768LL, 0, 1, 128, 0,
             256, 128, 4352, 32, 1.f, 0, nullptr);
        // a1 = softmax(SCALE * Q @ KL^T)  (hoisted before pinv)
        split(QKV, LNHh, LNHl, 6680064LL, 128LL, 4, 1536, 4352, 128, 32, SCALE_F);   // Q
        gemmbt(LNHh, LNHl, 557056LL, KLh, KLl, 32768LL,
               A3, 1114112LL, 256, 0,
               4352, 256, 128, 32, 0, nullptr);
        softmax256_k<<<34816, 256, 0, stream>>>(A3);
        // pinv(a2): temps in LNH arena (Q-split dead)
        pinv_absmax_k<<<32, 256, 0, stream>>>(A2, RED);
        pinv_scalar_k<<<1, 1, 0, stream>>>(RED, RED + 64);
        pinv_tinit_k<<<8192, 256, 0, stream>>>(A2, RED + 64, Zb0);
        float* zc = Zb0; float* zn = Zb1;
        for (int it = 0; it < 6; ++it) {
            gemm(A2, 65536LL, 0, 1, 256, 0, zc, 65536LL, 0, 1, 256, 1,
                 XZm, 65536LL, 0, 1, 256, 0, 256, 256, 256, 32, 1.f, 0, nullptr);
            gemmx(XZm, 65536LL, 0, 1, 256, 0, XZm, 65536LL, 0, 1, 256, 1,
                  U1, 65536LL, 0, 1, 256, 0, 256, 256, 256, 32, 1.f, 0, nullptr,
                  7.f, 1, 15.f, 1);
            gemmx(XZm, 65536LL, 0, 1, 256, 0, U1, 65536LL, 0, 1, 256, 1,
                  U2, 65536LL, 0, 1, 256, 0, 256, 256, 256, 32, 1.f, 0, nullptr,
                  0.f, 0, 13.f, 1);
            gemm(zc, 65536LL, 0, 1, 256, 0, U2, 65536LL, 0, 1, 256, 1,
                 zn, 65536LL, 0, 1, 256, 0, 256, 256, 256, 32, 0.25f, 0, nullptr);
            float* t2 = zc; zc = zn; zn = t2;
        }
        // ZKV = pinv @ KV  (overwrites KL-split region, which is now dead)
        gemm(zc, 65536LL, 0, 1, 256, 0,
             KV, 32768LL, 0, 1, 128, 1,
             ZKV, 32768LL, 0, 1, 128, 0,
             256, 128, 256, 32, 1.f, 0, nullptr);
        // ATT2 = a1 @ ZKV  (legacy path; writes f32 into LNH arena)
        gemm(A3, 1114112LL, 0, 1, 256, 0,
             ZKV, 32768LL, 0, 1, 128, 1,
             LNH, 2228224LL, 128LL, 4, 512, 0,
             4352, 128, 256, 32, 1.f, 0, nullptr);
        resconv_k<<<65552, 256, 0, stream>>>(QKV, res_k[L], LNH);
        // H0 += ATT2[PADR:] @ out_w + out_b  (pre-split path)
        split(LNH + PADR * 512, ATh, ATl, 2228224LL, 0, 1, 512, 4097, 512, 8, 1.f);
        splitT_k<<<1024, 256, 0, stream>>>(out_w[L], Wh, owl, 512, 512);
        gemmbt(ATh, ATl, 2097664LL, Wh, owl, 0,
               H0, 2097664LL, 512, 0,
               4097, 512, 512, BATCH, 1, out_b[L]);

        if (L == 0) {
            hipMemsetAsync(Tpad, 0, TPAD_FLOATS * sizeof(float), stream);
            wsum_k<<<101, 256, 0, stream>>>(k7, k5, k3, b7, b5, b3, WSUM);
            tin_k<<<dim3(64, 8, 8), 256, 0, stream>>>(H0, Tpad);
            conv7_k<<<4096, 256, 0, stream>>>(Tpad, WSUM, Tout);
            tout_k<<<dim3(64, 8, 8), 256, 0, stream>>>(Tout, H0);
        }
    }

    head_k<<<BATCH, 256, 0, stream>>>(H0, norm_g, norm_b, cls_w, cls_b, out);
}